// Round 5
// baseline (827.645 us; speedup 1.0000x reference)
//
#include <hip/hip_runtime.h>
#include <hip/hip_bf16.h>

#define T_TOK 4096
#define HDIM  1024
#define FDIM  4096
#define NEXP  8
#define CAP   4096
#define NTMAX 64                  // 256-row tiles: sum ceil(M_e/256) <= 40
#define OBR   8192                // compact rows (sum counts == 8192 exactly)

typedef __attribute__((ext_vector_type(8))) short short8;
typedef __attribute__((ext_vector_type(4))) float floatx4;
typedef __attribute__((ext_vector_type(4))) float float4v;
typedef __attribute__((ext_vector_type(4))) unsigned short ushort4v;

__device__ __forceinline__ unsigned short f2bf(float f) {
    union { float f; unsigned int u; } v; v.f = f;
    unsigned int u = v.u;
    u += 0x7fffu + ((u >> 16) & 1u);   // round-to-nearest-even
    return (unsigned short)(u >> 16);
}

__device__ __forceinline__ void gl2lds16(const void* g, void* l) {
    __builtin_amdgcn_global_load_lds(
        (const __attribute__((address_space(1))) unsigned int*)g,
        (__attribute__((address_space(3))) unsigned int*)l,
        16, 0, 0);
}

// ---------------- transpose + cast: src [R][C] fp32 -> dst [C][R] bf16, 64x64 tiles ----------------
__global__ void k_transpose_cast(const float* __restrict__ src, unsigned short* __restrict__ dst,
                                 int R, int C) {
    __shared__ float tile[64][65];
    size_t base = (size_t)blockIdx.z * (size_t)R * (size_t)C;
    int c0 = blockIdx.x * 64, r0 = blockIdx.y * 64;
    int lx = threadIdx.x & 15, ly = threadIdx.x >> 4;
#pragma unroll
    for (int i = 0; i < 4; ++i) {
        int rr = i * 16 + ly;
        float4v v = *(const float4v*)(src + base + (size_t)(r0 + rr) * C + c0 + lx * 4);
        tile[rr][lx * 4 + 0] = v[0]; tile[rr][lx * 4 + 1] = v[1];
        tile[rr][lx * 4 + 2] = v[2]; tile[rr][lx * 4 + 3] = v[3];
    }
    __syncthreads();
#pragma unroll
    for (int i = 0; i < 4; ++i) {
        int cc = i * 16 + ly;
        ushort4v o = { f2bf(tile[lx * 4 + 0][cc]), f2bf(tile[lx * 4 + 1][cc]),
                       f2bf(tile[lx * 4 + 2][cc]), f2bf(tile[lx * 4 + 3][cc]) };
        *(ushort4v*)(dst + base + (size_t)(c0 + cc) * R + r0 + lx * 4) = o;
    }
}

// merged wg+wu transpose (same shape): blockIdx.z = matrix*8 + expert
__global__ void k_transpose_cast2(const float* __restrict__ s0, const float* __restrict__ s1,
                                  unsigned short* __restrict__ d0, unsigned short* __restrict__ d1) {
    const int R = HDIM, C = FDIM;
    __shared__ float tile[64][65];
    int m = blockIdx.z >> 3, zz = blockIdx.z & 7;
    const float* src = (m ? s1 : s0);
    unsigned short* dst = (m ? d1 : d0);
    size_t base = (size_t)zz * (size_t)R * (size_t)C;
    int c0 = blockIdx.x * 64, r0 = blockIdx.y * 64;
    int lx = threadIdx.x & 15, ly = threadIdx.x >> 4;
#pragma unroll
    for (int i = 0; i < 4; ++i) {
        int rr = i * 16 + ly;
        float4v v = *(const float4v*)(src + base + (size_t)(r0 + rr) * C + c0 + lx * 4);
        tile[rr][lx * 4 + 0] = v[0]; tile[rr][lx * 4 + 1] = v[1];
        tile[rr][lx * 4 + 2] = v[2]; tile[rr][lx * 4 + 3] = v[3];
    }
    __syncthreads();
#pragma unroll
    for (int i = 0; i < 4; ++i) {
        int cc = i * 16 + ly;
        ushort4v o = { f2bf(tile[lx * 4 + 0][cc]), f2bf(tile[lx * 4 + 1][cc]),
                       f2bf(tile[lx * 4 + 2][cc]), f2bf(tile[lx * 4 + 3][cc]) };
        *(ushort4v*)(dst + base + (size_t)(c0 + cc) * R + r0 + lx * 4) = o;
    }
}

// ---------------- router (+ x cast): logits, softmax, top-2, lists, per-token slots ----------------
__global__ void k_router(const float* __restrict__ x, const float* __restrict__ wgate,
                         unsigned short* __restrict__ xb,
                         int* __restrict__ counts, int* __restrict__ ltok,
                         float* __restrict__ lwt, int* __restrict__ tslot) {
    int lane = threadIdx.x & 63;
    int tok = blockIdx.x * 4 + (threadIdx.x >> 6);
    const float* xr = x + (size_t)tok * HDIM;
    unsigned short* xbr = xb + (size_t)tok * HDIM;
    float acc[NEXP];
#pragma unroll
    for (int e = 0; e < NEXP; ++e) acc[e] = 0.f;
    for (int it = 0; it < HDIM / 256; ++it) {
        int h0 = it * 256 + lane * 4;
        float4v xv = *(const float4v*)(xr + h0);
        ushort4v xo = { f2bf(xv[0]), f2bf(xv[1]), f2bf(xv[2]), f2bf(xv[3]) };
        *(ushort4v*)(xbr + h0) = xo;
#pragma unroll
        for (int j = 0; j < 4; ++j) {
            float4v w0 = *(const float4v*)(wgate + (size_t)(h0 + j) * NEXP);
            float4v w1 = *(const float4v*)(wgate + (size_t)(h0 + j) * NEXP + 4);
            float xs = xv[j];
            acc[0] += xs * w0[0]; acc[1] += xs * w0[1];
            acc[2] += xs * w0[2]; acc[3] += xs * w0[3];
            acc[4] += xs * w1[0]; acc[5] += xs * w1[1];
            acc[6] += xs * w1[2]; acc[7] += xs * w1[3];
        }
    }
#pragma unroll
    for (int off = 32; off >= 1; off >>= 1)
#pragma unroll
        for (int e = 0; e < NEXP; ++e)
            acc[e] += __shfl_xor(acc[e], off, 64);
    if (lane == 0) {
        float m = acc[0];
#pragma unroll
        for (int e = 1; e < NEXP; ++e) m = fmaxf(m, acc[e]);
        float p[NEXP], s = 0.f;
#pragma unroll
        for (int e = 0; e < NEXP; ++e) { p[e] = __expf(acc[e] - m); s += p[e]; }
        float inv = 1.f / s;
#pragma unroll
        for (int e = 0; e < NEXP; ++e) p[e] *= inv;
        int e0 = 0; float b0 = p[0];
#pragma unroll
        for (int e = 1; e < NEXP; ++e) if (p[e] > b0) { b0 = p[e]; e0 = e; }
        int e1 = -1; float b1 = -1.f;
#pragma unroll
        for (int e = 0; e < NEXP; ++e) if (e != e0 && p[e] > b1) { b1 = p[e]; e1 = e; }
        int p0 = atomicAdd(&counts[e0], 1);
        ltok[e0 * CAP + p0] = tok; lwt[e0 * CAP + p0] = b0;
        int p1 = atomicAdd(&counts[e1], 1);
        ltok[e1 * CAP + p1] = tok; lwt[e1 * CAP + p1] = b1;
        tslot[tok * 2]     = (e0 << 16) | p0;
        tslot[tok * 2 + 1] = (e1 << 16) | p1;
    }
}

// prefix sums + compact (expert, 256-rowtile) worklist. sum ceil(M_e/256) <= 40.
__global__ void k_prefix(const int* __restrict__ counts, int* __restrict__ offs,
                         int* __restrict__ wl, int* __restrict__ nwl) {
    if (threadIdx.x == 0) {
        int s = 0;
#pragma unroll
        for (int e = 0; e < NEXP; ++e) { offs[e] = s; s += counts[e]; }
        int n = 0;
        for (int e = 0; e < NEXP; ++e)
            for (int r = 0; r * 256 < counts[e] && n < NTMAX; ++r)
                wl[n++] = (e << 8) | r;
        nwl[0] = n;
    }
}

// ---------------- GEMM1 v6: h = silu(x@Wg) * (x@Wu) ----------------
// BM=256 rows x (64 gate + 64 up) cols, BK=32. 512 threads / 8 waves (4M x 2N).
// Same proven 2-phase dbuf + both-sides chunk swizzle as v5, but 2x MFMA per
// barrier (128 vs 64) at the same 32 KB staged per step; B-traffic halved.
// LDS 48 KB -> 2 blocks/CU = 16 waves/CU (same 4 waves/SIMD TLP as v5).
__global__ __launch_bounds__(512, 4)
void k_gemm1(const unsigned short* __restrict__ xb,    // [T][H] bf16
             const unsigned short* __restrict__ wgt,   // [E][F][H] bf16
             const unsigned short* __restrict__ wut,   // [E][F][H]
             const int* __restrict__ counts, const int* __restrict__ offs,
             const int* __restrict__ ltok,
             const int* __restrict__ wl, const int* __restrict__ nwl,
             unsigned short* __restrict__ hbuf)        // [OBR][F] bf16
{
    const int bid = blockIdx.x;
    const int ftile = bid & 63;       // 0..63, consecutive bids share the A-panel
    const int by = bid >> 6;
    if (by >= nwl[0]) return;
    const int w = wl[by];
    const int e = w >> 8, rowtile = w & 255;
    const int M = counts[e];

    __shared__ __align__(16) unsigned short lA[2][256 * 32];   // 2 x 16 KB
    __shared__ __align__(16) unsigned short lBg[2][64 * 32];   // 2 x 4 KB
    __shared__ __align__(16) unsigned short lBu[2][64 * 32];   // 2 x 4 KB
    __shared__ int stok[256];

    const int t = threadIdx.x;
    const int wv = t >> 6, lane = t & 63;

    if (t < 256) {
        int i = rowtile * 256 + t;
        stok[t] = (i < M) ? ltok[e * CAP + i] : ltok[e * CAP];
    }
    __syncthreads();

    // staging: per K-step each thread issues 3 gl2lds (A x2, B x1).
    const int srow = wv * 16 + (lane >> 2);            // 0..127
    const int k4 = lane & 3;
    const int swA = (k4 ^ ((srow >> 1) & 3)) * 8;      // inverse-swizzled source chunk
    const unsigned short* pA0 = xb + (size_t)stok[srow] * HDIM + swA;
    const unsigned short* pA1 = xb + (size_t)stok[128 + srow] * HDIM + swA;
    const int brow = (wv & 3) * 16 + (lane >> 2);      // 0..63 (waves 0-3: g, 4-7: u)
    const int swB = (k4 ^ ((brow >> 1) & 3)) * 8;
    const unsigned short* wsrc = (wv < 4) ? wgt : wut;
    const unsigned short* pB = wsrc + ((size_t)e * FDIM + ftile * 64 + brow) * HDIM + swB;

    const int wm = wv >> 1, wn = wv & 1;
    const int fr = lane & 15, kg = lane >> 4;
    const int cswz = (kg ^ ((fr >> 1) & 3)) * 8;       // swizzled read chunk

    floatx4 accg[4][2], accu[4][2];
#pragma unroll
    for (int mi = 0; mi < 4; ++mi)
#pragma unroll
        for (int ni = 0; ni < 2; ++ni) {
            floatx4 z = {0.f, 0.f, 0.f, 0.f};
            accg[mi][ni] = z; accu[mi][ni] = z;
        }

    auto stage = [&](int b) {   // dest linear, wave-uniform base + lane*16
        gl2lds16(pA0, &lA[b][wv * 512]);        pA0 += 32;
        gl2lds16(pA1, &lA[b][4096 + wv * 512]); pA1 += 32;
        gl2lds16(pB, (wv < 4) ? &lBg[b][(wv & 3) * 512]
                              : &lBu[b][(wv & 3) * 512]);
        pB += 32;
    };
    auto compute = [&](int b) {
        short8 a[4], g[2], u[2];
#pragma unroll
        for (int mi = 0; mi < 4; ++mi)
            a[mi] = *(const short8*)&lA[b][(wm * 64 + mi * 16 + fr) * 32 + cswz];
#pragma unroll
        for (int ni = 0; ni < 2; ++ni) {
            g[ni] = *(const short8*)&lBg[b][(wn * 32 + ni * 16 + fr) * 32 + cswz];
            u[ni] = *(const short8*)&lBu[b][(wn * 32 + ni * 16 + fr) * 32 + cswz];
        }
#pragma unroll
        for (int mi = 0; mi < 4; ++mi)
#pragma unroll
            for (int ni = 0; ni < 2; ++ni) {
                accg[mi][ni] = __builtin_amdgcn_mfma_f32_16x16x32_bf16(a[mi], g[ni], accg[mi][ni], 0, 0, 0);
                accu[mi][ni] = __builtin_amdgcn_mfma_f32_16x16x32_bf16(a[mi], u[ni], accu[mi][ni], 0, 0, 0);
            }
    };

    // 32 K-steps of BK=32, double-buffered, stage-ahead by 1
    stage(0);
    __syncthreads();
#pragma unroll 1
    for (int it = 0; it < 16; ++it) {
        stage(1);
        compute(0);
        __syncthreads();
        if (it < 15) stage(0);
        compute(1);
        __syncthreads();
    }

    const int hrow0 = offs[e] + rowtile * 256;
#pragma unroll
    for (int mi = 0; mi < 4; ++mi)
#pragma unroll
        for (int ni = 0; ni < 2; ++ni) {
            int c = ftile * 64 + wn * 32 + ni * 16 + fr;
#pragma unroll
            for (int r = 0; r < 4; ++r) {
                int rr = wm * 64 + mi * 16 + kg * 4 + r;
                if (rowtile * 256 + rr < M) {
                    float g = accg[mi][ni][r];
                    float val = (g / (1.f + __expf(-g))) * accu[mi][ni][r];
                    hbuf[(size_t)(hrow0 + rr) * FDIM + c] = f2bf(val);
                }
            }
        }
}

// ---------------- GEMM2 v6: obuf[kq][row] = w * (h @ Wd^T), split-K=4 ----------------
// BM=256 rows x 128 h-cols, BK=32, K=1024 per block. Same 2-phase dbuf + swizzle.
// split-K=4 fixes tail packing: 1152 blocks on 512 slots (was 1136 on 1024 = 55%).
__global__ __launch_bounds__(512, 4)
void k_gemm2(const unsigned short* __restrict__ hbuf,  // [OBR][F] bf16
             const unsigned short* __restrict__ wdt,   // [E][H][F] bf16
             const int* __restrict__ counts, const int* __restrict__ offs,
             const float* __restrict__ lwt,
             const int* __restrict__ wl, const int* __restrict__ nwl,
             float* __restrict__ obuf)                 // [4][OBR][H] fp32
{
    const int bid = blockIdx.x;
    const int htile = bid & 7;        // 0..7
    const int kq = (bid >> 3) & 3;    // 0..3
    const int by = bid >> 5;
    if (by >= nwl[0]) return;
    const int w = wl[by];
    const int e = w >> 8, rowtile = w & 255;
    const int M = counts[e];

    __shared__ __align__(16) unsigned short lA[2][256 * 32];   // 2 x 16 KB
    __shared__ __align__(16) unsigned short lB[2][128 * 32];   // 2 x 8 KB
    __shared__ float swt[256];

    const int t = threadIdx.x;
    const int wv = t >> 6, lane = t & 63;

    if (t < 256) {
        int i = rowtile * 256 + t;
        swt[t] = (i < M) ? lwt[e * CAP + i] : 0.f;
    }

    const int row0 = offs[e] + rowtile * 256;
    const int srow = wv * 16 + (lane >> 2);            // 0..127
    const int k4 = lane & 3;
    const int sw = (k4 ^ ((srow >> 1) & 3)) * 8;
    const int kofs = kq * (FDIM / 4);
    // clamp A rows to the valid compact range (padded rows' results are discarded)
    const int ra0 = min(row0 + srow, OBR - 1);
    const int ra1 = min(row0 + 128 + srow, OBR - 1);
    const unsigned short* pA0 = hbuf + (size_t)ra0 * FDIM + kofs + sw;
    const unsigned short* pA1 = hbuf + (size_t)ra1 * FDIM + kofs + sw;
    const unsigned short* pB = wdt + ((size_t)e * HDIM + htile * 128 + srow) * FDIM + kofs + sw;

    const int wm = wv >> 1, wn = wv & 1;
    const int fr = lane & 15, kg = lane >> 4;
    const int cswz = (kg ^ ((fr >> 1) & 3)) * 8;

    floatx4 acc[4][4];
#pragma unroll
    for (int mi = 0; mi < 4; ++mi)
#pragma unroll
        for (int ni = 0; ni < 4; ++ni) {
            floatx4 z = {0.f, 0.f, 0.f, 0.f};
            acc[mi][ni] = z;
        }

    auto stage = [&](int b) {
        gl2lds16(pA0, &lA[b][wv * 512]);        pA0 += 32;
        gl2lds16(pA1, &lA[b][4096 + wv * 512]); pA1 += 32;
        gl2lds16(pB,  &lB[b][wv * 512]);        pB += 32;
    };
    auto compute = [&](int b) {
        short8 a[4], bb[4];
#pragma unroll
        for (int mi = 0; mi < 4; ++mi)
            a[mi] = *(const short8*)&lA[b][(wm * 64 + mi * 16 + fr) * 32 + cswz];
#pragma unroll
        for (int ni = 0; ni < 4; ++ni)
            bb[ni] = *(const short8*)&lB[b][(wn * 64 + ni * 16 + fr) * 32 + cswz];
#pragma unroll
        for (int mi = 0; mi < 4; ++mi)
#pragma unroll
            for (int ni = 0; ni < 4; ++ni)
                acc[mi][ni] = __builtin_amdgcn_mfma_f32_16x16x32_bf16(a[mi], bb[ni], acc[mi][ni], 0, 0, 0);
    };

    // 32 K-steps of BK=32 over this K-quarter, double-buffered, stage-ahead by 1
    stage(0);
    __syncthreads();
#pragma unroll 1
    for (int it = 0; it < 16; ++it) {
        stage(1);
        compute(0);
        __syncthreads();
        if (it < 15) stage(0);
        compute(1);
        __syncthreads();
    }

    float* ob = obuf + (size_t)kq * OBR * HDIM;
#pragma unroll
    for (int mi = 0; mi < 4; ++mi)
#pragma unroll
        for (int ni = 0; ni < 4; ++ni) {
            int c = htile * 128 + wn * 64 + ni * 16 + fr;
#pragma unroll
            for (int r = 0; r < 4; ++r) {
                int rr = wm * 64 + mi * 16 + kg * 4 + r;
                if (rowtile * 256 + rr < M)
                    ob[(size_t)(row0 + rr) * HDIM + c] = acc[mi][ni][r] * swt[rr];
            }
        }
}

// ---------------- combine: out[tok] = sum over 2 slots x 4 k-quarters ----------------
__global__ void k_combine(const float* __restrict__ obuf, const int* __restrict__ tslot,
                          const int* __restrict__ offs, float* __restrict__ out) {
    int gid = blockIdx.x * 256 + threadIdx.x;
    int tok = gid >> 8;           // 256 threads per token
    int c = (gid & 255) * 4;
    int s0 = tslot[tok * 2], s1 = tslot[tok * 2 + 1];
    size_t r0 = (size_t)(offs[s0 >> 16] + (s0 & 0xFFFF));
    size_t r1 = (size_t)(offs[s1 >> 16] + (s1 & 0xFFFF));
    float4v s = {0.f, 0.f, 0.f, 0.f};
#pragma unroll
    for (int q = 0; q < 4; ++q) {
        s += *(const float4v*)(obuf + ((size_t)q * OBR + r0) * HDIM + c);
        s += *(const float4v*)(obuf + ((size_t)q * OBR + r1) * HDIM + c);
    }
    *(float4v*)(out + (size_t)tok * HDIM + c) = s;
}

extern "C" void kernel_launch(void* const* d_in, const int* in_sizes, int n_in,
                              void* d_out, int out_size, void* d_ws, size_t ws_size,
                              hipStream_t stream) {
    const float* x     = (const float*)d_in[0];  // [4096][1024]
    const float* wgate = (const float*)d_in[1];  // [1024][8]
    const float* wg    = (const float*)d_in[2];  // [8][1024][4096]
    const float* wu    = (const float*)d_in[3];  // [8][1024][4096]
    const float* wd    = (const float*)d_in[4];  // [8][4096][1024]
    float* out = (float*)d_out;

    char* ws = (char*)d_ws;
    size_t off = 0;
    unsigned short* xb  = (unsigned short*)(ws + off); off += (size_t)T_TOK * HDIM * 2;
    unsigned short* wgt = (unsigned short*)(ws + off); off += (size_t)NEXP * FDIM * HDIM * 2;
    unsigned short* wut = (unsigned short*)(ws + off); off += (size_t)NEXP * FDIM * HDIM * 2;
    unsigned short* wdt = (unsigned short*)(ws + off); off += (size_t)NEXP * HDIM * FDIM * 2;
    unsigned short* hbuf= (unsigned short*)(ws + off); off += (size_t)OBR * FDIM * 2;
    int*   ltok   = (int*)(ws + off);   off += (size_t)NEXP * CAP * 4;
    float* lwt    = (float*)(ws + off); off += (size_t)NEXP * CAP * 4;
    int*   tslot  = (int*)(ws + off);   off += (size_t)T_TOK * 2 * 4;
    int*   counts = (int*)(ws + off);   off += 256;
    int*   offs   = (int*)(ws + off);   off += 256;
    int*   wl     = (int*)(ws + off);   off += NTMAX * 4;
    int*   nwl    = (int*)(ws + off);   off += 256;
    // obuf aliases wgt+wut (dead after gemm1): 4*OBR*HDIM*4 = 134.2 MB == wgt+wut bytes
    float* obuf = (float*)wgt;

    hipMemsetAsync(counts, 0, 32, stream);

    k_router<<<T_TOK / 4, 256, 0, stream>>>(x, wgate, xb, counts, ltok, lwt, tslot);
    k_transpose_cast2<<<dim3(FDIM / 64, HDIM / 64, 16), 256, 0, stream>>>(wg, wu, wgt, wut);
    k_transpose_cast<<<dim3(HDIM / 64, FDIM / 64, NEXP), 256, 0, stream>>>(wd, wdt, FDIM, HDIM);
    k_prefix<<<1, 64, 0, stream>>>(counts, offs, wl, nwl);
    k_gemm1<<<64 * 40, 512, 0, stream>>>(xb, wgt, wut, counts, offs, ltok, wl, nwl, hbuf);
    k_gemm2<<<32 * 40, 512, 0, stream>>>(hbuf, wdt, counts, offs, lwt, wl, nwl, obuf);
    k_combine<<<T_TOK * HDIM / 1024, 256, 0, stream>>>(obuf, tslot, offs, out);
}